// Round 6
// baseline (787.176 us; speedup 1.0000x reference)
//
#include <hip/hip_runtime.h>
#include <hip/hip_bf16.h>
#include <math.h>

// ---------------------------------------------------------------------------
// Quantized CNN forward (bitwise-exact vs fp32 reference):
//   block_k: maxpool2( quant_act( conv3x3(x, quant_weight(wk)), ak ) )
//   then global max over HxW, then 1x1 conv (10x128).
// quant_act is monotone => commutes with maxpool (pool raw conv, quantize once).
// CRITICAL: per-output accumulation stays (ci asc, k asc) with FMA — bitwise
// match in rounds 1-5 (absmax 0.0). Only tiling/scheduling changes.
//
// R6: R5 hit 61% VALUBusy but (256,5)'s 102-reg cap vs ~115 live respilled
// (WRITE 16->41.5MB). Fix = raise FMA density instead of fighting the cap:
// NCO=16 per thread (576 FMA/ci, ~92% density, half the redundant z-group
// staging) + flat unpadded LDS tile (34*34) so ds_writes are base+imm-offset
// (slots = tid+256s) — staging state shrinks to 5 sidx + 5 v regs. Live ~115
// fits (256,4)=128 cap with no spills, 4 waves/SIMD, depth-2 pipeline kept.
// ---------------------------------------------------------------------------

__global__ __launch_bounds__(64)
void prep_zero(unsigned* __restrict__ maxb) {
    if (threadIdx.x < 4) maxb[threadIdx.x] = 0u;
}

__global__ __launch_bounds__(256)
void prep_absmax(const float* __restrict__ w1, const float* __restrict__ w2,
                 const float* __restrict__ w3, const float* __restrict__ wc,
                 unsigned* __restrict__ maxb) {
    const float* srcs[4] = {w1, w2, w3, wc};
    const int    ns[4]   = {32*3*9, 64*32*9, 128*64*9, 10*128};
    const int t = blockIdx.y;
    const float* s = srcs[t];
    const int    N = ns[t];
    float m = 0.f;
    for (int i = blockIdx.x * 256 + threadIdx.x; i < N; i += 16 * 256)
        m = fmaxf(m, fabsf(s[i]));
    #pragma unroll
    for (int o = 32; o > 0; o >>= 1) m = fmaxf(m, __shfl_down(m, o));
    __shared__ float red[4];
    const int lane = threadIdx.x & 63, wid = threadIdx.x >> 6;
    if (lane == 0) red[wid] = m;
    __syncthreads();
    if (threadIdx.x == 0) {
        float mm = fmaxf(fmaxf(red[0], red[1]), fmaxf(red[2], red[3]));
        atomicMax(maxb + t, __float_as_uint(mm));  // |w|>=0: uint order == float order
    }
}

__global__ __launch_bounds__(256)
void prep_quant(const float* __restrict__ w1, const float* __restrict__ w2,
                const float* __restrict__ w3, const float* __restrict__ wc,
                const unsigned* __restrict__ maxb,
                float* __restrict__ q1, float* __restrict__ q2,
                float* __restrict__ q3, float* __restrict__ qc) {
    const float* srcs[4] = {w1, w2, w3, wc};
    float*       dsts[4] = {q1, q2, q3, qc};
    const int    ns[4]   = {32*3*9, 64*32*9, 128*64*9, 10*128};
    const int t = blockIdx.y;
    const float* s = srcs[t];
    float*       d = dsts[t];
    const int    N = ns[t];
    const float sc = fmaxf(__uint_as_float(maxb[t]), 1e-8f);  // qmax = 2^(2-1)-1 = 1
    for (int i = blockIdx.x * 256 + threadIdx.x; i < N; i += 16 * 256)
        d[i] = rintf(s[i] / sc) * sc;
}

// Fused conv3x3(pad=1) + maxpool2 + quant_act.
// 16x16 threads; each thread: 1 pooled pixel x 16 output channels (64 accs).
// Tile: 16x16 pooled = 32x32 conv px; LDS 34x34 FLAT (no pad), 2 buffers.
// Staging slot s of thread tid covers flat index tid+256*s -> ds_write with
// immediate offsets. Register pipeline depth 2 (loads age one compute phase).
template<int CIN>
__global__ __launch_bounds__(256, 4)
void conv_act_pool(const float* __restrict__ in, const float* __restrict__ qw,
                   const float* __restrict__ alpha_p, float* __restrict__ out,
                   int Co, int H, int W) {
    const int PH = H >> 1, PW = W >> 1;
    const int tx = threadIdx.x, ty = threadIdx.y;
    const int tid = ty * 16 + tx;
    const int ngrp = Co >> 4;
    const int b    = blockIdx.z / ngrp;
    const int co0  = (blockIdx.z % ngrp) * 16;
    const int px   = blockIdx.x * 16 + tx;       // pooled col
    const int py   = blockIdx.y * 16 + ty;       // pooled row
    const int ix0  = blockIdx.x * 32 - 1;        // input col of tile col 0
    const int iy0  = blockIdx.y * 32 - 1;        // input row of tile row 0

    __shared__ float tile[2][34 * 34];
    const float* inB = in + (size_t)b * CIN * H * W;

    // Staging slots hoisted once: sidx<0 encodes "write zero" (pad/out-of-img).
    int sidx[5];
    #pragma unroll
    for (int s = 0; s < 5; ++s) {
        const int idx = tid + 256 * s;
        const int r = idx / 34, c = idx - r * 34;
        const int gy = iy0 + r, gx = ix0 + c;
        const bool ok = (idx < 34 * 34) &&
                        (gy >= 0) && (gy < H) && (gx >= 0) && (gx < W);
        sidx[s] = ok ? (gy * W + gx) : -1;
    }

    float v[5];   // in-flight staged values (register pipeline)
    auto load_regs = [&](int ci) {
        const float* inC = inB + (size_t)ci * H * W;
        #pragma unroll
        for (int s = 0; s < 5; ++s)
            v[s] = (sidx[s] >= 0) ? inC[sidx[s]] : 0.f;
    };
    auto store_tile = [&](int buf) {
        float* t = tile[buf];
        #pragma unroll
        for (int s = 0; s < 5; ++s) {
            const int idx = tid + 256 * s;          // imm-offset ds_write
            if (s < 4 || idx < 34 * 34) t[idx] = v[s];
        }
    };

    float acc[16][4];   // [out-ch][2x2 prepool]
    #pragma unroll
    for (int c = 0; c < 16; ++c)
        #pragma unroll
        for (int p = 0; p < 4; ++p) acc[c][p] = 0.f;

    // Pipeline prologue: buf0 <- ch0; regs <- ch1.
    load_regs(0);
    store_tile(0);
    if (CIN > 1) load_regs(1);
    __syncthreads();

    #pragma unroll 2
    for (int ci = 0; ci < CIN; ++ci) {
        const int buf = ci & 1;
        if (ci + 1 < CIN) {
            store_tile(buf ^ 1);                 // v holds ci+1 (loads aged ~1 iter)
            if (ci + 2 < CIN) load_regs(ci + 2); // issue next loads early
        }

        // 4x4 patch covering this thread's 2x2 conv outputs; float2 reads
        float p[4][4];
        const float* t = tile[buf];
        #pragma unroll
        for (int r = 0; r < 4; ++r) {
            const int base = (2 * ty + r) * 34 + 2 * tx;   // even -> 8B aligned
            const float2 q0 = *(const float2*)&t[base];
            const float2 q1 = *(const float2*)&t[base + 2];
            p[r][0] = q0.x; p[r][1] = q0.y; p[r][2] = q1.x; p[r][3] = q1.y;
        }

        #pragma unroll
        for (int c = 0; c < 16; ++c) {
            const float* wp = qw + ((size_t)(co0 + c) * CIN + ci) * 9;  // uniform
            float w[9];
            #pragma unroll
            for (int k = 0; k < 9; ++k) w[k] = wp[k];
            #pragma unroll
            for (int k = 0; k < 9; ++k) {
                const int ky = k / 3, kx = k % 3;
                acc[c][0] += w[k] * p[ky + 0][kx + 0];
                acc[c][1] += w[k] * p[ky + 0][kx + 1];
                acc[c][2] += w[k] * p[ky + 1][kx + 0];
                acc[c][3] += w[k] * p[ky + 1][kx + 1];
            }
        }
        __syncthreads();
    }

    if (py < PH && px < PW) {
        const float alpha = *alpha_p;
        const float scale = alpha / 3.0f;    // 2^ABITS - 1 = 3
        #pragma unroll
        for (int c = 0; c < 16; ++c) {
            const float m = fmaxf(fmaxf(acc[c][0], acc[c][1]),
                                  fmaxf(acc[c][2], acc[c][3]));
            const float y = fminf(fmaxf(m, 0.f), alpha);
            out[(((size_t)b * Co + co0 + c) * PH + py) * PW + px] =
                rintf(y / scale) * scale;
        }
    }
}

// One wave per (channel, batch): global max over 28x28.
__global__ __launch_bounds__(64)
void gmax_kernel(const float* __restrict__ h3, float* __restrict__ g) {
    const int c = blockIdx.x, b = blockIdx.y;
    const float* p = h3 + ((size_t)b * 128 + c) * 784;
    float m = -INFINITY;
    for (int i = threadIdx.x; i < 784; i += 64) m = fmaxf(m, p[i]);
    #pragma unroll
    for (int o = 32; o > 0; o >>= 1) m = fmaxf(m, __shfl_down(m, o));
    if (threadIdx.x == 0) g[b * 128 + c] = m;
}

// 1x1 conv 128->10 per batch (same k-ascending FMA order as round 1).
__global__ __launch_bounds__(128)
void classify_kernel(const float* __restrict__ g, const float* __restrict__ qwc,
                     float* __restrict__ out) {
    const int b = blockIdx.x;
    __shared__ float gg[128];
    gg[threadIdx.x] = g[b * 128 + threadIdx.x];
    __syncthreads();
    if (threadIdx.x < 10) {
        float s = 0.f;
        for (int k = 0; k < 128; ++k) s += qwc[threadIdx.x * 128 + k] * gg[k];
        out[b * 10 + threadIdx.x] = s;
    }
}

extern "C" void kernel_launch(void* const* d_in, const int* in_sizes, int n_in,
                              void* d_out, int out_size, void* d_ws, size_t ws_size,
                              hipStream_t stream) {
    const float* x  = (const float*)d_in[0];
    const float* w1 = (const float*)d_in[1];
    const float* w2 = (const float*)d_in[2];
    const float* w3 = (const float*)d_in[3];
    const float* wc = (const float*)d_in[4];
    const float* a1 = (const float*)d_in[5];
    const float* a2 = (const float*)d_in[6];
    const float* a3 = (const float*)d_in[7];

    float* ws = (float*)d_ws;
    size_t o = 0;
    float* qw1 = ws + o; o += 32 * 3 * 9;
    float* qw2 = ws + o; o += 64 * 32 * 9;
    float* qw3 = ws + o; o += 128 * 64 * 9;
    float* qwc = ws + o; o += 10 * 128;
    unsigned* maxb = (unsigned*)(ws + o); o += 4;
    float* g   = ws + o; o += 32 * 128;
    float* h1p = ws + o; o += 32UL * 32 * 112 * 112;
    float* h2p = ws + o; o += 32UL * 64 * 56 * 56;
    float* h3p = ws + o; o += 32UL * 128 * 28 * 28;

    prep_zero<<<1, 64, 0, stream>>>(maxb);
    prep_absmax<<<dim3(16, 4), 256, 0, stream>>>(w1, w2, w3, wc, maxb);
    prep_quant<<<dim3(16, 4), 256, 0, stream>>>(w1, w2, w3, wc, maxb,
                                                qw1, qw2, qw3, qwc);

    // conv1: 3->32, 224x224 -> pooled 112x112. tiles 7x7, z = 32b * 2 grp
    conv_act_pool<3><<<dim3(7, 7, 32 * (32 / 16)), dim3(16, 16), 0, stream>>>(
        x, qw1, a1, h1p, 32, 224, 224);
    // conv2: 32->64, pooled 56x56. tiles 4x4, z = 32b * 4 grp
    conv_act_pool<32><<<dim3(4, 4, 32 * (64 / 16)), dim3(16, 16), 0, stream>>>(
        h1p, qw2, a2, h2p, 64, 112, 112);
    // conv3: 64->128, pooled 28x28. tiles 2x2, z = 32b * 8 grp
    conv_act_pool<64><<<dim3(2, 2, 32 * (128 / 16)), dim3(16, 16), 0, stream>>>(
        h2p, qw3, a3, h3p, 128, 56, 56);

    gmax_kernel<<<dim3(128, 32), 64, 0, stream>>>(h3p, g);
    classify_kernel<<<32, 128, 0, stream>>>(g, qwc, (float*)d_out);
}

// Round 7
// 558.539 us; speedup vs baseline: 1.4093x; 1.4093x over previous
//
#include <hip/hip_runtime.h>
#include <hip/hip_bf16.h>
#include <math.h>

// ---------------------------------------------------------------------------
// Quantized CNN forward (bitwise-exact vs fp32 reference):
//   block_k: maxpool2( quant_act( conv3x3(x, quant_weight(wk)), ak ) )
//   then global max over HxW, then 1x1 conv (10x128).
// quant_act is monotone => commutes with maxpool (pool raw conv, quantize once).
//
// R7: SPARSE reformulation. quant_weight with WBITS=2 gives ternary {-s,0,+s}
// and ~95-97% zeros (threshold s/2 ~ 2sigma). Skipping zero-weight FMAs is
// IEEE-bitwise-exact: fma(0,a,acc)=acc (acc starts +0, (+0)+(-0)=+0, exact
// cancellations give +0), and fl(+-s * a) is the very product the reference
// rounds. We enumerate nonzeros per (co, ci-chunk) in (ci asc, k asc) order
// (the order that matched XLA bitwise in R1-R6) into CSR lists, then
// accumulate only those. ~20x fewer FMAs; live regs ~90 (acc dominates) so
// NCO=16 finally fits (256,4) without the R2/R5/R6 spills.
// ---------------------------------------------------------------------------

__global__ __launch_bounds__(64)
void prep_zero(unsigned* __restrict__ maxb) {
    if (threadIdx.x < 4) maxb[threadIdx.x] = 0u;
}

__global__ __launch_bounds__(256)
void prep_absmax(const float* __restrict__ w1, const float* __restrict__ w2,
                 const float* __restrict__ w3, const float* __restrict__ wc,
                 unsigned* __restrict__ maxb) {
    const float* srcs[4] = {w1, w2, w3, wc};
    const int    ns[4]   = {32*3*9, 64*32*9, 128*64*9, 10*128};
    const int t = blockIdx.y;
    const float* s = srcs[t];
    const int    N = ns[t];
    float m = 0.f;
    for (int i = blockIdx.x * 256 + threadIdx.x; i < N; i += 16 * 256)
        m = fmaxf(m, fabsf(s[i]));
    #pragma unroll
    for (int o = 32; o > 0; o >>= 1) m = fmaxf(m, __shfl_down(m, o));
    __shared__ float red[4];
    const int lane = threadIdx.x & 63, wid = threadIdx.x >> 6;
    if (lane == 0) red[wid] = m;
    __syncthreads();
    if (threadIdx.x == 0) {
        float mm = fmaxf(fmaxf(red[0], red[1]), fmaxf(red[2], red[3]));
        atomicMax(maxb + t, __float_as_uint(mm));  // |w|>=0: uint order == float order
    }
}

__global__ __launch_bounds__(256)
void prep_quant(const float* __restrict__ w1, const float* __restrict__ w2,
                const float* __restrict__ w3, const float* __restrict__ wc,
                const unsigned* __restrict__ maxb,
                float* __restrict__ q1, float* __restrict__ q2,
                float* __restrict__ q3, float* __restrict__ qc) {
    const float* srcs[4] = {w1, w2, w3, wc};
    float*       dsts[4] = {q1, q2, q3, qc};
    const int    ns[4]   = {32*3*9, 64*32*9, 128*64*9, 10*128};
    const int t = blockIdx.y;
    const float* s = srcs[t];
    float*       d = dsts[t];
    const int    N = ns[t];
    const float sc = fmaxf(__uint_as_float(maxb[t]), 1e-8f);  // qmax = 2^(2-1)-1 = 1
    for (int i = blockIdx.x * 256 + threadIdx.x; i < N; i += 16 * 256)
        d[i] = rintf(s[i] / sc) * sc;
}

// Build CSR of nonzero ternary weights per (co, ci-chunk-of-8), entries in
// (ci asc, k asc) order — the reference accumulation order. One block/layer.
// Entry: eoff = ci*1156 + ky*34 + kx (word offset in the full-channel tile
// geometry; kernel subtracts the chunk base), ecoef = the +-s weight itself.
__global__ __launch_bounds__(256)
void build_csr(const float* __restrict__ qw, int Co, int CIN,
               int* __restrict__ rowptr, int* __restrict__ eoff,
               float* __restrict__ ecoef) {
    const int nchunk = (CIN + 7) / 8;
    const int nrows = Co * nchunk;
    __shared__ int cnt[1024];
    __shared__ int rowsum[128];
    const int t = threadIdx.x;
    for (int rc = t; rc < nrows; rc += 256) {
        const int co = rc / nchunk, ch = rc - co * nchunk;
        const int c0 = ch * 8, c1 = min(CIN, c0 + 8);
        int n = 0;
        for (int ci = c0; ci < c1; ++ci)
            for (int k = 0; k < 9; ++k)
                if (qw[(co * CIN + ci) * 9 + k] != 0.f) ++n;
        cnt[rc] = n;
    }
    __syncthreads();
    if (t < Co) {
        int s = 0;
        for (int ch = 0; ch < nchunk; ++ch) s += cnt[t * nchunk + ch];
        rowsum[t] = s;
    }
    __syncthreads();
    if (t == 0) {
        int s = 0;
        for (int co = 0; co < Co; ++co) { int c = rowsum[co]; rowsum[co] = s; s += c; }
    }
    __syncthreads();
    if (t < Co) {
        int s = rowsum[t];
        for (int ch = 0; ch < nchunk; ++ch) {
            rowptr[t * nchunk + ch] = s;
            const int c = cnt[t * nchunk + ch];
            cnt[t * nchunk + ch] = s;            // start position for emit
            s += c;
        }
        if (t == Co - 1) rowptr[nrows] = s;
    }
    __syncthreads();
    for (int rc = t; rc < nrows; rc += 256) {
        const int co = rc / nchunk, ch = rc - co * nchunk;
        const int c0 = ch * 8, c1 = min(CIN, c0 + 8);
        int pos = cnt[rc];
        for (int ci = c0; ci < c1; ++ci)
            for (int k = 0; k < 9; ++k) {
                const float w = qw[(co * CIN + ci) * 9 + k];
                if (w != 0.f) {
                    eoff[pos]  = ci * 1156 + (k / 3) * 34 + (k % 3);
                    ecoef[pos] = w;
                    ++pos;
                }
            }
    }
}

// Sparse fused conv3x3(pad=1) + maxpool2 + quant_act.
// 16x16 threads over a 16x16 pooled tile (32x32 conv px, 34x34 input tile).
// ci processed in chunks of 8 staged to LDS; per co, walk the uniform CSR
// entry list: 4 ds_read_b32 + 4 FMA per nonzero weight.
template<int CIN, int Co, int NCO>
__global__ __launch_bounds__(256, 4)
void conv_sparse(const float* __restrict__ in, const int* __restrict__ rowptr,
                 const int* __restrict__ eoff, const float* __restrict__ ecoef,
                 const float* __restrict__ alpha_p, float* __restrict__ out,
                 int H, int W) {
    constexpr int NCHUNK = (CIN + 7) / 8;
    constexpr int CCH    = (CIN < 8) ? CIN : 8;
    constexpr int NGRP   = Co / NCO;
    const int PH = H >> 1, PW = W >> 1;
    const int tx = threadIdx.x, ty = threadIdx.y;
    const int b   = blockIdx.z / NGRP;           // NGRP constexpr pow2 -> shift
    const int co0 = (blockIdx.z % NGRP) * NCO;
    const int px  = blockIdx.x * 16 + tx;
    const int py  = blockIdx.y * 16 + ty;
    const int ix0 = blockIdx.x * 32 - 1;
    const int iy0 = blockIdx.y * 32 - 1;

    __shared__ float tile[CCH * 1156];           // chunk-local [ci][34][34] flat
    const size_t HW = (size_t)H * W;
    const float* inB = in + (size_t)b * CIN * HW;

    // Staging slot indices hoisted once; -1 = zero-fill (pad / out of image).
    int sidx[3][3];
    #pragma unroll
    for (int i = 0; i < 3; ++i)
        #pragma unroll
        for (int j = 0; j < 3; ++j) {
            const int gy = iy0 + ty + 16 * i, gx = ix0 + tx + 16 * j;
            sidx[i][j] = (gy >= 0 && gy < H && gx >= 0 && gx < W)
                         ? (gy * W + gx) : -1;
        }

    float acc[NCO][4];
    #pragma unroll
    for (int c = 0; c < NCO; ++c)
        #pragma unroll
        for (int p = 0; p < 4; ++p) acc[c][p] = 0.f;

    const int base = (2 * ty) * 34 + 2 * tx;     // word offset of thread's patch

    for (int chunk = 0; chunk < NCHUNK; ++chunk) {
        __syncthreads();                          // protect previous compute
        const int ch0 = chunk * 8;
        #pragma unroll
        for (int ch = 0; ch < CCH; ++ch) {        // CIN%8==0 or CIN<8: full
            const float* inC = inB + (size_t)(ch0 + ch) * HW;
            #pragma unroll
            for (int i = 0; i < 3; ++i) {
                if (i < 2 || ty < 2) {
                    const int r = ty + 16 * i;
                    #pragma unroll
                    for (int j = 0; j < 3; ++j) {
                        if (j < 2 || tx < 2) {
                            const int c = tx + 16 * j;
                            const int s = sidx[i][j];
                            float v = 0.f;
                            if (s >= 0) v = inC[s];
                            tile[ch * 1156 + r * 34 + c] = v;
                        }
                    }
                }
            }
        }
        __syncthreads();

        const int cbase = ch0 * 1156;
        #pragma unroll
        for (int c = 0; c < NCO; ++c) {
            const int row = (co0 + c) * NCHUNK + chunk;
            const int r1 = rowptr[row + 1];       // uniform -> scalar
            for (int e = rowptr[row]; e < r1; ++e) {
                const float coef = ecoef[e];                       // uniform
                const float* tp  = tile + (eoff[e] - cbase) + base;
                acc[c][0] = fmaf(coef, tp[0],  acc[c][0]);
                acc[c][1] = fmaf(coef, tp[1],  acc[c][1]);
                acc[c][2] = fmaf(coef, tp[34], acc[c][2]);
                acc[c][3] = fmaf(coef, tp[35], acc[c][3]);
            }
        }
    }

    if (py < PH && px < PW) {
        const float alpha = *alpha_p;
        const float scale = alpha / 3.0f;         // 2^ABITS - 1 = 3
        #pragma unroll
        for (int c = 0; c < NCO; ++c) {
            const float m = fmaxf(fmaxf(acc[c][0], acc[c][1]),
                                  fmaxf(acc[c][2], acc[c][3]));
            const float y = fminf(fmaxf(m, 0.f), alpha);
            out[(((size_t)b * Co + co0 + c) * PH + py) * PW + px] =
                rintf(y / scale) * scale;
        }
    }
}

// One wave per (channel, batch): global max over 28x28.
__global__ __launch_bounds__(64)
void gmax_kernel(const float* __restrict__ h3, float* __restrict__ g) {
    const int c = blockIdx.x, b = blockIdx.y;
    const float* p = h3 + ((size_t)b * 128 + c) * 784;
    float m = -INFINITY;
    for (int i = threadIdx.x; i < 784; i += 64) m = fmaxf(m, p[i]);
    #pragma unroll
    for (int o = 32; o > 0; o >>= 1) m = fmaxf(m, __shfl_down(m, o));
    if (threadIdx.x == 0) g[b * 128 + c] = m;
}

// 1x1 conv 128->10 per batch (same k-ascending FMA order as round 1).
__global__ __launch_bounds__(128)
void classify_kernel(const float* __restrict__ g, const float* __restrict__ qwc,
                     float* __restrict__ out) {
    const int b = blockIdx.x;
    __shared__ float gg[128];
    gg[threadIdx.x] = g[b * 128 + threadIdx.x];
    __syncthreads();
    if (threadIdx.x < 10) {
        float s = 0.f;
        for (int k = 0; k < 128; ++k) s += qwc[threadIdx.x * 128 + k] * gg[k];
        out[b * 10 + threadIdx.x] = s;
    }
}

extern "C" void kernel_launch(void* const* d_in, const int* in_sizes, int n_in,
                              void* d_out, int out_size, void* d_ws, size_t ws_size,
                              hipStream_t stream) {
    const float* x  = (const float*)d_in[0];
    const float* w1 = (const float*)d_in[1];
    const float* w2 = (const float*)d_in[2];
    const float* w3 = (const float*)d_in[3];
    const float* wc = (const float*)d_in[4];
    const float* a1 = (const float*)d_in[5];
    const float* a2 = (const float*)d_in[6];
    const float* a3 = (const float*)d_in[7];

    float* ws = (float*)d_ws;
    size_t o = 0;
    float* qw1 = ws + o; o += 32 * 3 * 9;
    float* qw2 = ws + o; o += 64 * 32 * 9;
    float* qw3 = ws + o; o += 128 * 64 * 9;
    float* qwc = ws + o; o += 10 * 128;
    unsigned* maxb = (unsigned*)(ws + o); o += 4;
    float* g   = ws + o; o += 32 * 128;
    int*   rp1 = (int*)(ws + o); o += 32 * 1 + 1;
    int*   rp2 = (int*)(ws + o); o += 64 * 4 + 1;
    int*   rp3 = (int*)(ws + o); o += 128 * 8 + 1;
    int*   eo1 = (int*)(ws + o); o += 32 * 3 * 9;
    float* ec1 = ws + o;         o += 32 * 3 * 9;
    int*   eo2 = (int*)(ws + o); o += 64 * 32 * 9;
    float* ec2 = ws + o;         o += 64 * 32 * 9;
    int*   eo3 = (int*)(ws + o); o += 128 * 64 * 9;
    float* ec3 = ws + o;         o += 128 * 64 * 9;
    float* h1p = ws + o; o += 32UL * 32 * 112 * 112;
    float* h2p = ws + o; o += 32UL * 64 * 56 * 56;
    float* h3p = ws + o; o += 32UL * 128 * 28 * 28;

    prep_zero<<<1, 64, 0, stream>>>(maxb);
    prep_absmax<<<dim3(16, 4), 256, 0, stream>>>(w1, w2, w3, wc, maxb);
    prep_quant<<<dim3(16, 4), 256, 0, stream>>>(w1, w2, w3, wc, maxb,
                                                qw1, qw2, qw3, qwc);
    build_csr<<<1, 256, 0, stream>>>(qw1, 32, 3,  rp1, eo1, ec1);
    build_csr<<<1, 256, 0, stream>>>(qw2, 64, 32, rp2, eo2, ec2);
    build_csr<<<1, 256, 0, stream>>>(qw3, 128, 64, rp3, eo3, ec3);

    // conv1: 3->32, 224x224 -> pooled 112x112. tiles 7x7, z = 32b * 2 grp
    conv_sparse<3, 32, 16><<<dim3(7, 7, 32 * 2), dim3(16, 16), 0, stream>>>(
        x, rp1, eo1, ec1, a1, h1p, 224, 224);
    // conv2: 32->64, pooled 56x56. tiles 4x4, z = 32b * 4 grp
    conv_sparse<32, 64, 16><<<dim3(4, 4, 32 * 4), dim3(16, 16), 0, stream>>>(
        h1p, rp2, eo2, ec2, a2, h2p, 112, 112);
    // conv3: 64->128, pooled 28x28. tiles 2x2, z = 32b * 8 grp
    conv_sparse<64, 128, 16><<<dim3(2, 2, 32 * 8), dim3(16, 16), 0, stream>>>(
        h2p, rp3, eo3, ec3, a3, h3p, 56, 56);

    gmax_kernel<<<dim3(128, 32), 64, 0, stream>>>(h3p, g);
    classify_kernel<<<32, 128, 0, stream>>>(g, qwc, (float*)d_out);
}